// Round 5
// baseline (150.029 us; speedup 1.0000x reference)
//
#include <hip/hip_runtime.h>
#include <hip/hip_bf16.h>
#include <cstdint>
#include <cstddef>

// ---------- types ----------
typedef __bf16 bf16x8 __attribute__((ext_vector_type(8)));
typedef float f32x4 __attribute__((ext_vector_type(4)));

__device__ __forceinline__ void gload_lds16(const void* g, void* l) {
  __builtin_amdgcn_global_load_lds((const __attribute__((address_space(1))) void*)g,
                                   (__attribute__((address_space(3))) void*)l, 16, 0, 0);
}

__device__ __forceinline__ unsigned short f2bf(float x) {
  return __builtin_bit_cast(unsigned short, __float2bfloat16(x));
}

// ---------- kernel 1: fused Fc + W prep (bf16 LDS staging, 33 KB) ----------
__global__ void __launch_bounds__(256) prep_kernel(const float* __restrict__ TF,
                                                   const float* __restrict__ SF,
                                                   __hip_bfloat16* __restrict__ Wt,
                                                   __hip_bfloat16* __restrict__ Ws) {
  __shared__ __hip_bfloat16 Xs[16 * 1040];
  __shared__ float scale[16];
  int id = blockIdx.x;              // [0,1024): t[1] b[4] cb[5]
  int t = id >> 9, b = (id >> 5) & 15, cb = id & 31;
  const float* Xg = (t ? SF : TF) + ((size_t)b * 512 + (size_t)cb * 16) * 1024;
  __hip_bfloat16* W = (t ? Ws : Wt) + (size_t)b * 524288 + cb * 16;
  int tid = threadIdx.x;
  int ch = tid >> 4, seg = tid & 15;
  const float* rowp = Xg + (size_t)ch * 1024 + seg * 64;
  float s = 0.f;
#pragma unroll
  for (int i = 0; i < 16; ++i) {
    float4 v = *reinterpret_cast<const float4*>(rowp + i * 4);
    s += fabsf(v.x) + fabsf(v.y) + fabsf(v.z) + fabsf(v.w);
    ushort4 hv;
    hv.x = f2bf(v.x); hv.y = f2bf(v.y);
    hv.z = f2bf(v.z); hv.w = f2bf(v.w);
    *reinterpret_cast<ushort4*>(&Xs[ch * 1040 + seg * 64 + i * 4]) = hv;
  }
  s += __shfl_xor(s, 1); s += __shfl_xor(s, 2);
  s += __shfl_xor(s, 4); s += __shfl_xor(s, 8);
  if (seg == 0) scale[ch] = sqrtf(s);
  __syncthreads();
  float sc[16];
#pragma unroll
  for (int c = 0; c < 16; ++c) sc[c] = scale[c];
#pragma unroll
  for (int j = 0; j < 4; ++j) {
    int m = j * 256 + tid;
    union { unsigned short h[16]; uint4 u[2]; } pk;
#pragma unroll
    for (int c = 0; c < 16; ++c)
      pk.h[c] = f2bf(__bfloat162float(Xs[c * 1040 + m]) * sc[c]);
    uint4* dst = reinterpret_cast<uint4*>(W + (size_t)m * 512);
    dst[0] = pk.u[0];
    dst[1] = pk.u[1];
  }
}

// ---------- kernel 2: fused SYRK, 128x64 bricks, BK=32 double-buffered ----------
// 1152 jobs = 16 batches x 36 pairs x 2 halves. 256 thr = 4 waves (2x2), per-wave 64x32.
__global__ void __launch_bounds__(256, 4) syrk_fused_kernel(
    const __hip_bfloat16* __restrict__ Wt, const __hip_bfloat16* __restrict__ Ws,
    float* __restrict__ nT, float* __restrict__ nS, float* __restrict__ cross) {
  __shared__ __hip_bfloat16 As2[2][128 * 32];   // 16 KB
  __shared__ __hip_bfloat16 Bs2[2][64 * 32];    // 8 KB
  int bid = blockIdx.x;                       // 1152 = 8 XCD * 144
  int j = (bid & 7) * 144 + (bid >> 3);       // bijective XCD swizzle: 2 batches/XCD
  int b = j / 72, r72 = j % 72;
  int p = r72 >> 1, h = r72 & 1;
  int bx = p, tm = 0;
  while (bx >= 8 - tm) { bx -= 8 - tm; ++tm; }
  int tn = tm + bx;
  bool diag = (tm == tn);
  const __hip_bfloat16* WTb = Wt + (size_t)b * 524288;
  const __hip_bfloat16* WSb = Ws + (size_t)b * 524288;
  const __hip_bfloat16* At = WTb + (size_t)tm * 65536;
  const __hip_bfloat16* Asrc = WSb + (size_t)tm * 65536;
  const __hip_bfloat16* Btg = WTb + (size_t)(tn * 128 + h * 64) * 512;
  const __hip_bfloat16* Bsg = WSb + (size_t)(tn * 128 + h * 64) * 512;

  const int tid = threadIdx.x;
  const int lane = tid & 63, wv = tid >> 6;
  const int wr = wv >> 1, wc = wv & 1;
  const int g = lane >> 4, c0 = lane & 15;
  const int kc = (g ^ ((c0 >> 1) & 3)) * 8;   // swizzled K-chunk offset (lane-const)

  f32x4 accT[4][2], accS[4][2];
#pragma unroll
  for (int mi = 0; mi < 4; ++mi)
#pragma unroll
    for (int ni = 0; ni < 2; ++ni) {
      accT[mi][ni] = (f32x4){0.f, 0.f, 0.f, 0.f};
      accS[mi][ni] = (f32x4){0.f, 0.f, 0.f, 0.f};
    }

  // stage step s into buffer buf
  auto stage = [&](int s, int buf) {
    int kt = (s & 15) * 32;
    const __hip_bfloat16* Ab = (s < 16) ? At : Asrc;
#pragma unroll
    for (int i = 0; i < 2; ++i) {
      int ci = i * 256 + tid;
      int row = ci >> 2, slot = ci & 3;
      int gs = slot ^ ((row >> 1) & 3);
      gload_lds16(Ab + (size_t)row * 512 + kt + gs * 8, &As2[buf][(i * 256 + wv * 64) * 8]);
    }
    if (!diag) {
      const __hip_bfloat16* Bb = (s < 16) ? Btg : Bsg;
      int row = tid >> 2, slot = tid & 3;
      int gs = slot ^ ((row >> 1) & 3);
      gload_lds16(Bb + (size_t)row * 512 + kt + gs * 8, &Bs2[buf][(wv * 64) * 8]);
    }
  };

  stage(0, 0);
  __syncthreads();

  for (int s = 0; s < 32; ++s) {
    int cur = s & 1;
    if (s < 31) stage(s + 1, cur ^ 1);
    const __hip_bfloat16* Asb = As2[cur];
    const __hip_bfloat16* Bsb = diag ? (As2[cur] + h * 64 * 32) : Bs2[cur];
    bf16x8 a[4], bb[2];
#pragma unroll
    for (int mi = 0; mi < 4; ++mi)
      a[mi] = *reinterpret_cast<const bf16x8*>(Asb + (wr * 64 + mi * 16 + c0) * 32 + kc);
#pragma unroll
    for (int ni = 0; ni < 2; ++ni)
      bb[ni] = *reinterpret_cast<const bf16x8*>(Bsb + (wc * 32 + ni * 16 + c0) * 32 + kc);
    if (s < 16) {
#pragma unroll
      for (int mi = 0; mi < 4; ++mi)
#pragma unroll
        for (int ni = 0; ni < 2; ++ni)
          accT[mi][ni] = __builtin_amdgcn_mfma_f32_16x16x32_bf16(a[mi], bb[ni], accT[mi][ni], 0, 0, 0);
    } else {
#pragma unroll
      for (int mi = 0; mi < 4; ++mi)
#pragma unroll
        for (int ni = 0; ni < 2; ++ni)
          accS[mi][ni] = __builtin_amdgcn_mfma_f32_16x16x32_bf16(a[mi], bb[ni], accS[mi][ni], 0, 0, 0);
    }
    __syncthreads();
  }

  float* pT = nT + (size_t)b * 1024;
  float* pS = nS + (size_t)b * 1024;
  float* pC = cross + (size_t)b * 1024;
  // row-direction sums (over this brick's 64 columns)
#pragma unroll
  for (int mi = 0; mi < 4; ++mi)
#pragma unroll
    for (int r = 0; r < 4; ++r) {
      float sT = 0.f, sS = 0.f, sC = 0.f;
#pragma unroll
      for (int ni = 0; ni < 2; ++ni) {
        float tv = accT[mi][ni][r], sv = accS[mi][ni][r];
        sT += tv * tv; sS += sv * sv; sC += tv * sv;
      }
#pragma unroll
      for (int msk = 1; msk < 16; msk <<= 1) {
        sT += __shfl_xor(sT, msk); sS += __shfl_xor(sS, msk); sC += __shfl_xor(sC, msk);
      }
      if (c0 == 0) {
        int m = tm * 128 + wr * 64 + mi * 16 + g * 4 + r;
        atomicAdd(pT + m, sT); atomicAdd(pS + m, sS); atomicAdd(pC + m, sC);
      }
    }
  // column-direction (transpose) sums, off-diagonal bricks only
  if (!diag) {
#pragma unroll
    for (int ni = 0; ni < 2; ++ni) {
      float sT = 0.f, sS = 0.f, sC = 0.f;
#pragma unroll
      for (int mi = 0; mi < 4; ++mi)
#pragma unroll
        for (int r = 0; r < 4; ++r) {
          float tv = accT[mi][ni][r], sv = accS[mi][ni][r];
          sT += tv * tv; sS += sv * sv; sC += tv * sv;
        }
      sT += __shfl_xor(sT, 16); sS += __shfl_xor(sS, 16); sC += __shfl_xor(sC, 16);
      sT += __shfl_xor(sT, 32); sS += __shfl_xor(sS, 32); sC += __shfl_xor(sC, 32);
      if (g == 0) {
        int n = tn * 128 + h * 64 + wc * 32 + ni * 16 + c0;
        atomicAdd(pT + n, sT); atomicAdd(pS + n, sS); atomicAdd(pC + n, sC);
      }
    }
  }
}

// ---------- kernel 3: channel grams + fused s_out passthrough ----------
__global__ void __launch_bounds__(256) icgram2_kernel(const float* __restrict__ t_out,
                                                      const float* __restrict__ s_out,
                                                      float* __restrict__ G,
                                                      float* __restrict__ outcpy) {
  __shared__ float lds[22 * 516];
  int chunk = blockIdx.x;   // 32 chunks of 512 m
  int z = blockIdx.y;       // t*16 + b
  int t = z >> 4, bb = z & 15;
  const float* L = (t ? s_out : t_out) + (size_t)bb * 344064 + (size_t)chunk * 512;
  float* O = outcpy + (size_t)bb * 344064 + (size_t)chunk * 512;
  int tid = threadIdx.x;    // 256 threads
  for (int idx = tid; idx < 22 * 128; idx += 256) {
    int r = idx >> 7, c = idx & 127;
    float4 v;
    if (r < 21) {
      v = *reinterpret_cast<const float4*>(L + (size_t)r * 16384 + c * 4);
      if (t) *reinterpret_cast<float4*>(O + (size_t)r * 16384 + c * 4) = v;
    } else { v.x = 0.f; v.y = 0.f; v.z = 0.f; v.w = 0.f; }
    *reinterpret_cast<float4*>(&lds[r * 516 + c * 4]) = v;
  }
  __syncthreads();
  int ms = tid & 3;
  for (int pb = tid >> 2; pb < 66; pb += 64) {
    int pp = pb, gi = 0;
    while (pp >= 11 - gi) { pp -= 11 - gi; gi++; }
    int gj = gi + pp;
    const float* ri0 = &lds[(2 * gi) * 516 + ms * 128];
    const float* ri1 = ri0 + 516;
    const float* rj0 = &lds[(2 * gj) * 516 + ms * 128];
    const float* rj1 = rj0 + 516;
    float a00 = 0.f, a01 = 0.f, a10 = 0.f, a11 = 0.f;
#pragma unroll
    for (int mi = 0; mi < 32; ++mi) {
      float4 va0 = *reinterpret_cast<const float4*>(ri0 + mi * 4);
      float4 va1 = *reinterpret_cast<const float4*>(ri1 + mi * 4);
      float4 vb0 = *reinterpret_cast<const float4*>(rj0 + mi * 4);
      float4 vb1 = *reinterpret_cast<const float4*>(rj1 + mi * 4);
      a00 += va0.x * vb0.x + va0.y * vb0.y + va0.z * vb0.z + va0.w * vb0.w;
      a01 += va0.x * vb1.x + va0.y * vb1.y + va0.z * vb1.z + va0.w * vb1.w;
      a10 += va1.x * vb0.x + va1.y * vb0.y + va1.z * vb0.z + va1.w * vb0.w;
      a11 += va1.x * vb1.x + va1.y * vb1.y + va1.z * vb1.z + va1.w * vb1.w;
    }
    a00 += __shfl_xor(a00, 1); a00 += __shfl_xor(a00, 2);
    a01 += __shfl_xor(a01, 1); a01 += __shfl_xor(a01, 2);
    a10 += __shfl_xor(a10, 1); a10 += __shfl_xor(a10, 2);
    a11 += __shfl_xor(a11, 1); a11 += __shfl_xor(a11, 2);
    if (ms == 0) {
      float* Gz = G + (size_t)z * 441;
      int i0 = 2 * gi, i1 = i0 + 1, j0 = 2 * gj, j1 = j0 + 1;
      atomicAdd(&Gz[i0 * 21 + j0], a00);
      if (j1 < 21) atomicAdd(&Gz[i0 * 21 + j1], a01);
      if (i1 < 21 && gi != gj) atomicAdd(&Gz[i1 * 21 + j0], a10);
      if (i1 < 21 && j1 < 21) atomicAdd(&Gz[i1 * 21 + j1], a11);
    }
  }
}

// ---------- kernel 4: finalize both losses ----------
__global__ void finalize_kernel(const float* __restrict__ G, const float* __restrict__ nT,
                                const float* __restrict__ nS, const float* __restrict__ cross,
                                float* __restrict__ out2) {
  __shared__ float red[16];
  int tid = threadIdx.x;   // 1024
  float sa = 0.f;
#pragma unroll
  for (int it = 0; it < 4; ++it) {
    int i4 = it * 1024 + tid;
    float4 a = reinterpret_cast<const float4*>(nT)[i4];
    float4 s4 = reinterpret_cast<const float4*>(nS)[i4];
    float4 c4 = reinterpret_cast<const float4*>(cross)[i4];
#pragma unroll
    for (int k = 0; k < 4; ++k) {
      float a1 = (&a.x)[k], s1 = (&s4.x)[k], c1 = (&c4.x)[k];
      float NT = fmaxf(sqrtf(a1), 1e-12f), NS = fmaxf(sqrtf(s1), 1e-12f);
      sa += a1 / (NT * NT) + s1 / (NS * NS) - 2.f * c1 / (NT * NS);
    }
  }
  float ic = 0.f;
  if (tid < 336) {
    int b = tid / 21, i = tid % 21;
    const float* gt = G + (size_t)b * 441;
    const float* gs = G + (size_t)(16 + b) * 441;
    float nt = 0.f, ns = 0.f;
    for (int j = 0; j < 21; ++j) {
      int idx2 = (i <= j) ? i * 21 + j : j * 21 + i;
      float vt = gt[idx2], vs = gs[idx2];
      nt += vt * vt; ns += vs * vs;
    }
    float rt = 1.f / fmaxf(sqrtf(nt), 1e-12f);
    float rs = 1.f / fmaxf(sqrtf(ns), 1e-12f);
    for (int j = 0; j < 21; ++j) {
      int idx2 = (i <= j) ? i * 21 + j : j * 21 + i;
      float d = gs[idx2] * rs - gt[idx2] * rt;
      ic += d * d;
    }
  }
  int lane = tid & 63, wv = tid >> 6;
#pragma unroll
  for (int m = 32; m; m >>= 1) { sa += __shfl_xor(sa, m); ic += __shfl_xor(ic, m); }
  if (lane == 0) red[wv] = sa;
  __syncthreads();
  if (tid == 0) { float s = 0.f; for (int w = 0; w < 16; ++w) s += red[w]; out2[1] = s * (1.0f / 16777216.0f); }
  __syncthreads();
  if (lane == 0) red[wv] = ic;
  __syncthreads();
  if (tid == 0) { float s = 0.f; for (int w = 0; w < 16; ++w) s += red[w]; out2[0] = s * (1.0f / 336.0f); }
}

// ---------- launch ----------
extern "C" void kernel_launch(void* const* d_in, const int* in_sizes, int n_in,
                              void* d_out, int out_size, void* d_ws, size_t ws_size,
                              hipStream_t stream) {
  const float* TF = (const float*)d_in[0];
  const float* SF = (const float*)d_in[1];
  const float* t_out = (const float*)d_in[2];
  const float* s_out = (const float*)d_in[3];
  float* out = (float*)d_out;
  char* ws = (char*)d_ws;

  // ws layout (bytes):
  //   0        : nT    [16][1024] f32  (65536)
  //   65536    : nS    [16][1024] f32  (65536)
  //   131072   : cross [16][1024] f32  (65536)
  //   196608   : G     [32][441]  f32  (56448, zeroed through 253056)
  //   262144   : Wt bf16 [16][1024][512] (16777216)
  //   17039360 : Ws bf16 [16][1024][512] (16777216)  -> total ~33.8 MB
  float* nT = (float*)(ws + 0);
  float* nS = (float*)(ws + 65536);
  float* cross = (float*)(ws + 131072);
  float* G = (float*)(ws + 196608);
  __hip_bfloat16* Wt = (__hip_bfloat16*)(ws + 262144);
  __hip_bfloat16* Ws = (__hip_bfloat16*)(ws + 262144 + 16777216);

  (void)hipMemsetAsync(ws, 0, 253056, stream);   // nT, nS, cross, G

  prep_kernel<<<1024, 256, 0, stream>>>(TF, SF, Wt, Ws);
  syrk_fused_kernel<<<1152, 256, 0, stream>>>(Wt, Ws, nT, nS, cross);
  icgram2_kernel<<<dim3(32, 32), 256, 0, stream>>>(t_out, s_out, G, out);
  finalize_kernel<<<1, 1024, 0, stream>>>(G, nT, nS, cross, out + 5505024);
}

// Round 6
// 130.525 us; speedup vs baseline: 1.1494x; 1.1494x over previous
//
#include <hip/hip_runtime.h>
#include <hip/hip_bf16.h>
#include <cstdint>
#include <cstddef>

// ---------- types ----------
typedef __bf16 bf16x8 __attribute__((ext_vector_type(8)));
typedef float f32x4 __attribute__((ext_vector_type(4)));

__device__ __forceinline__ void gload_lds16(const void* g, void* l) {
  __builtin_amdgcn_global_load_lds((const __attribute__((address_space(1))) void*)g,
                                   (__attribute__((address_space(3))) void*)l, 16, 0, 0);
}
__device__ __forceinline__ unsigned short f2bf(float x) {
  return __builtin_bit_cast(unsigned short, __float2bfloat16(x));
}
#define S_BARRIER asm volatile("s_barrier" ::: "memory")
#define WAIT_VM(N) asm volatile("s_waitcnt vmcnt(" #N ")" ::: "memory")

// ---------- kernel 1: sqrtFc[t][b][c] = sqrt(sum_m |X[b][c][m]|) ----------
__global__ void fc_kernel(const float* __restrict__ TF, const float* __restrict__ SF,
                          float* __restrict__ sqrtFc) {
  int wv = threadIdx.x >> 6, lane = threadIdx.x & 63;
  int row = blockIdx.x * 4 + wv;                 // [0, 16384)
  const float* X = (row < 8192) ? TF : SF;
  const float* p = X + (size_t)(row & 8191) * 1024;
  float s = 0.f;
#pragma unroll
  for (int it = 0; it < 4; ++it) {
    float4 v = *reinterpret_cast<const float4*>(p + (size_t)(it * 64 + lane) * 4);
    s += fabsf(v.x) + fabsf(v.y) + fabsf(v.z) + fabsf(v.w);
  }
#pragma unroll
  for (int m = 32; m; m >>= 1) s += __shfl_xor(s, m);
  if (lane == 0) sqrtFc[row] = sqrtf(s);
}

// ---------- kernel 2: W[b][m][c] = bf16(X[b][c][m] * sqrtFc[b][c]), 64x64 tiles ----------
__global__ void __launch_bounds__(256) wprep2_kernel(const float* __restrict__ TF,
                                                     const float* __restrict__ SF,
                                                     const float* __restrict__ sqrtFc,
                                                     __hip_bfloat16* __restrict__ Wt,
                                                     __hip_bfloat16* __restrict__ Ws) {
  __shared__ float lds[64][65];
  __shared__ float scale[64];
  int z = blockIdx.z;                // t*16 + b
  int t = z >> 4, b = z & 15;
  int m0 = blockIdx.x * 64, c0 = blockIdx.y * 64;
  const float* Xg = (t ? SF : TF) + (size_t)b * 524288;
  __hip_bfloat16* Wg = (t ? Ws : Wt) + (size_t)b * 524288;
  int tid = threadIdx.x;
  if (tid < 64) scale[tid] = sqrtFc[t * 8192 + b * 512 + c0 + tid];
  // read 64 c-rows x 64 m (256B contiguous runs)
#pragma unroll
  for (int i = 0; i < 4; ++i) {
    int v = i * 256 + tid;
    int r = v >> 4, q = v & 15;
    *reinterpret_cast<float4*>(&lds[r][q * 4]) =
        *reinterpret_cast<const float4*>(Xg + (size_t)(c0 + r) * 1024 + m0 + q * 4);
  }
  __syncthreads();
  // write 64 m-rows x 64 c (128B contiguous runs of bf16)
#pragma unroll
  for (int jj = 0; jj < 2; ++jj) {
    int m = jj * 32 + (tid >> 3), oct = tid & 7;
    union { unsigned short h[8]; uint4 u; } pk;
#pragma unroll
    for (int k = 0; k < 8; ++k) {
      int c = oct * 8 + k;
      pk.h[k] = f2bf(lds[c][m] * scale[c]);
    }
    *reinterpret_cast<uint4*>(Wg + (size_t)(m0 + m) * 512 + c0 + oct * 8) = pk.u;
  }
}

// ---------- kernel 3: fused SYRK, counted-vmcnt pipeline ----------
// 576 jobs = 16 batches x 36 upper-tri pairs. 512 thr = 8 waves (4x2), per-wave 32x64.
// BK=64 double-buffered; prefetch stays in flight across barriers (vmcnt(4), never 0).
__global__ void __launch_bounds__(512, 4) syrk_fused_kernel(
    const __hip_bfloat16* __restrict__ Wt, const __hip_bfloat16* __restrict__ Ws,
    float* __restrict__ nT, float* __restrict__ nS, float* __restrict__ cross) {
  __shared__ __hip_bfloat16 AL[2][128 * 64];    // 32 KB
  __shared__ __hip_bfloat16 BL[2][128 * 64];    // 32 KB
  int bid = blockIdx.x;                       // 576 = 8 XCD * 72
  int j = (bid & 7) * 72 + (bid >> 3);        // bijective XCD swizzle: 2 batches/XCD
  int b = j / 36, pair = j % 36;
  int bx = pair, tm = 0;
  while (bx >= 8 - tm) { bx -= 8 - tm; ++tm; }
  int tn = tm + bx;
  bool diag = (tm == tn);
  const __hip_bfloat16* WTb = Wt + (size_t)b * 524288;
  const __hip_bfloat16* WSb = Ws + (size_t)b * 524288;
  const __hip_bfloat16* ATp = WTb + (size_t)tm * 65536;
  const __hip_bfloat16* ASp = WSb + (size_t)tm * 65536;
  const __hip_bfloat16* BTp = WTb + (size_t)tn * 65536;
  const __hip_bfloat16* BSp = WSb + (size_t)tn * 65536;

  const int tid = threadIdx.x;
  const int lane = tid & 63, wv = tid >> 6;
  const int wr = wv >> 1, wc = wv & 1;       // 4x2 wave grid
  const int g = lane >> 4, c0 = lane & 15, cx = c0 & 7;

  // staging: 1024 16B-chunks per 128x64 tile; 2 per thread; swizzled global source
  int offs[2], dst[2];
#pragma unroll
  for (int i = 0; i < 2; ++i) {
    int ci = i * 512 + tid;
    int row = ci >> 3, slot = ci & 7;
    offs[i] = row * 512 + (slot ^ (row & 7)) * 8;
    dst[i] = (i * 512 + wv * 64) * 8;        // wave-uniform base; HW adds lane*16B
  }

  f32x4 accT[2][4], accS[2][4];
#pragma unroll
  for (int mi = 0; mi < 2; ++mi)
#pragma unroll
    for (int ni = 0; ni < 4; ++ni) {
      accT[mi][ni] = (f32x4){0.f, 0.f, 0.f, 0.f};
      accS[mi][ni] = (f32x4){0.f, 0.f, 0.f, 0.f};
    }

  auto stage = [&](int s, int buf) {
    int kt = (s & 7) * 64;
    const __hip_bfloat16* Ab = (s < 8) ? ATp : ASp;
    const __hip_bfloat16* Bb = (s < 8) ? BTp : BSp;
#pragma unroll
    for (int i = 0; i < 2; ++i) {
      gload_lds16(Ab + offs[i] + kt, &AL[buf][dst[i]]);
      gload_lds16(Bb + offs[i] + kt, &BL[buf][dst[i]]);
    }
  };

  stage(0, 0);
#pragma unroll
  for (int s = 0; s < 16; ++s) {             // 0-7: T, 8-15: S
    int buf = s & 1;
    if (s < 15) {
      stage(s + 1, buf ^ 1);
      WAIT_VM(4);                            // wait stage(s); stage(s+1) stays in flight
    } else {
      WAIT_VM(0);
    }
    S_BARRIER;
    const __hip_bfloat16* Ab = AL[buf];
    const __hip_bfloat16* Bb = BL[buf];
#pragma unroll
    for (int kk = 0; kk < 2; ++kk) {
      int ck = ((kk * 4 + g) ^ cx) * 8;
      bf16x8 av[2], bv[4];
#pragma unroll
      for (int mi = 0; mi < 2; ++mi)
        av[mi] = *reinterpret_cast<const bf16x8*>(Ab + (wr * 32 + mi * 16 + c0) * 64 + ck);
#pragma unroll
      for (int ni = 0; ni < 4; ++ni)
        bv[ni] = *reinterpret_cast<const bf16x8*>(Bb + (wc * 64 + ni * 16 + c0) * 64 + ck);
      if (s < 8) {
#pragma unroll
        for (int mi = 0; mi < 2; ++mi)
#pragma unroll
          for (int ni = 0; ni < 4; ++ni)
            accT[mi][ni] = __builtin_amdgcn_mfma_f32_16x16x32_bf16(av[mi], bv[ni], accT[mi][ni], 0, 0, 0);
      } else {
#pragma unroll
        for (int mi = 0; mi < 2; ++mi)
#pragma unroll
          for (int ni = 0; ni < 4; ++ni)
            accS[mi][ni] = __builtin_amdgcn_mfma_f32_16x16x32_bf16(av[mi], bv[ni], accS[mi][ni], 0, 0, 0);
      }
    }
    if (s < 15) S_BARRIER;                   // all reads of buf done before overwrite
  }

  float* pT = nT + (size_t)b * 1024;
  float* pS = nS + (size_t)b * 1024;
  float* pC = cross + (size_t)b * 1024;
  // row-direction sums (over this tile's 128 columns)
#pragma unroll
  for (int mi = 0; mi < 2; ++mi)
#pragma unroll
    for (int r = 0; r < 4; ++r) {
      float sT = 0.f, sS = 0.f, sC = 0.f;
#pragma unroll
      for (int ni = 0; ni < 4; ++ni) {
        float tv = accT[mi][ni][r], sv = accS[mi][ni][r];
        sT += tv * tv; sS += sv * sv; sC += tv * sv;
      }
#pragma unroll
      for (int msk = 1; msk < 16; msk <<= 1) {
        sT += __shfl_xor(sT, msk); sS += __shfl_xor(sS, msk); sC += __shfl_xor(sC, msk);
      }
      if (c0 == 0) {
        int m = tm * 128 + wr * 32 + mi * 16 + g * 4 + r;
        atomicAdd(pT + m, sT); atomicAdd(pS + m, sS); atomicAdd(pC + m, sC);
      }
    }
  // column-direction (transpose) sums, off-diagonal tiles only
  if (!diag) {
#pragma unroll
    for (int ni = 0; ni < 4; ++ni) {
      float sT = 0.f, sS = 0.f, sC = 0.f;
#pragma unroll
      for (int mi = 0; mi < 2; ++mi)
#pragma unroll
        for (int r = 0; r < 4; ++r) {
          float tv = accT[mi][ni][r], sv = accS[mi][ni][r];
          sT += tv * tv; sS += sv * sv; sC += tv * sv;
        }
      sT += __shfl_xor(sT, 16); sS += __shfl_xor(sS, 16); sC += __shfl_xor(sC, 16);
      sT += __shfl_xor(sT, 32); sS += __shfl_xor(sS, 32); sC += __shfl_xor(sC, 32);
      if (g == 0) {
        int n = tn * 128 + wc * 64 + ni * 16 + c0;
        atomicAdd(pT + n, sT); atomicAdd(pS + n, sS); atomicAdd(pC + n, sC);
      }
    }
  }
}

// ---------- kernel 4: channel grams + fused s_out passthrough ----------
__global__ void __launch_bounds__(256) icgram2_kernel(const float* __restrict__ t_out,
                                                      const float* __restrict__ s_out,
                                                      float* __restrict__ G,
                                                      float* __restrict__ outcpy) {
  __shared__ float lds[22 * 516];
  int chunk = blockIdx.x;   // 32 chunks of 512 m
  int z = blockIdx.y;       // t*16 + b
  int t = z >> 4, bb = z & 15;
  const float* L = (t ? s_out : t_out) + (size_t)bb * 344064 + (size_t)chunk * 512;
  float* O = outcpy + (size_t)bb * 344064 + (size_t)chunk * 512;
  int tid = threadIdx.x;    // 256 threads
  for (int idx = tid; idx < 22 * 128; idx += 256) {
    int r = idx >> 7, c = idx & 127;
    float4 v;
    if (r < 21) {
      v = *reinterpret_cast<const float4*>(L + (size_t)r * 16384 + c * 4);
      if (t) *reinterpret_cast<float4*>(O + (size_t)r * 16384 + c * 4) = v;
    } else { v.x = 0.f; v.y = 0.f; v.z = 0.f; v.w = 0.f; }
    *reinterpret_cast<float4*>(&lds[r * 516 + c * 4]) = v;
  }
  __syncthreads();
  int ms = tid & 3;
  for (int pb = tid >> 2; pb < 66; pb += 64) {
    int pp = pb, gi = 0;
    while (pp >= 11 - gi) { pp -= 11 - gi; gi++; }
    int gj = gi + pp;
    const float* ri0 = &lds[(2 * gi) * 516 + ms * 128];
    const float* ri1 = ri0 + 516;
    const float* rj0 = &lds[(2 * gj) * 516 + ms * 128];
    const float* rj1 = rj0 + 516;
    float a00 = 0.f, a01 = 0.f, a10 = 0.f, a11 = 0.f;
#pragma unroll
    for (int mi = 0; mi < 32; ++mi) {
      float4 va0 = *reinterpret_cast<const float4*>(ri0 + mi * 4);
      float4 va1 = *reinterpret_cast<const float4*>(ri1 + mi * 4);
      float4 vb0 = *reinterpret_cast<const float4*>(rj0 + mi * 4);
      float4 vb1 = *reinterpret_cast<const float4*>(rj1 + mi * 4);
      a00 += va0.x * vb0.x + va0.y * vb0.y + va0.z * vb0.z + va0.w * vb0.w;
      a01 += va0.x * vb1.x + va0.y * vb1.y + va0.z * vb1.z + va0.w * vb1.w;
      a10 += va1.x * vb0.x + va1.y * vb0.y + va1.z * vb0.z + va1.w * vb0.w;
      a11 += va1.x * vb1.x + va1.y * vb1.y + va1.z * vb1.z + va1.w * vb1.w;
    }
    a00 += __shfl_xor(a00, 1); a00 += __shfl_xor(a00, 2);
    a01 += __shfl_xor(a01, 1); a01 += __shfl_xor(a01, 2);
    a10 += __shfl_xor(a10, 1); a10 += __shfl_xor(a10, 2);
    a11 += __shfl_xor(a11, 1); a11 += __shfl_xor(a11, 2);
    if (ms == 0) {
      float* Gz = G + (size_t)z * 441;
      int i0 = 2 * gi, i1 = i0 + 1, j0 = 2 * gj, j1 = j0 + 1;
      atomicAdd(&Gz[i0 * 21 + j0], a00);
      if (j1 < 21) atomicAdd(&Gz[i0 * 21 + j1], a01);
      if (i1 < 21 && gi != gj) atomicAdd(&Gz[i1 * 21 + j0], a10);
      if (i1 < 21 && j1 < 21) atomicAdd(&Gz[i1 * 21 + j1], a11);
    }
  }
}

// ---------- kernel 5: finalize both losses ----------
__global__ void finalize_kernel(const float* __restrict__ G, const float* __restrict__ nT,
                                const float* __restrict__ nS, const float* __restrict__ cross,
                                float* __restrict__ out2) {
  __shared__ float red[16];
  int tid = threadIdx.x;   // 1024
  float sa = 0.f;
#pragma unroll
  for (int it = 0; it < 4; ++it) {
    int i4 = it * 1024 + tid;
    float4 a = reinterpret_cast<const float4*>(nT)[i4];
    float4 s4 = reinterpret_cast<const float4*>(nS)[i4];
    float4 c4 = reinterpret_cast<const float4*>(cross)[i4];
#pragma unroll
    for (int k = 0; k < 4; ++k) {
      float a1 = (&a.x)[k], s1 = (&s4.x)[k], c1 = (&c4.x)[k];
      float NT = fmaxf(sqrtf(a1), 1e-12f), NS = fmaxf(sqrtf(s1), 1e-12f);
      sa += a1 / (NT * NT) + s1 / (NS * NS) - 2.f * c1 / (NT * NS);
    }
  }
  float ic = 0.f;
  if (tid < 336) {
    int b = tid / 21, i = tid % 21;
    const float* gt = G + (size_t)b * 441;
    const float* gs = G + (size_t)(16 + b) * 441;
    float nt = 0.f, ns = 0.f;
    for (int j = 0; j < 21; ++j) {
      int idx2 = (i <= j) ? i * 21 + j : j * 21 + i;
      float vt = gt[idx2], vs = gs[idx2];
      nt += vt * vt; ns += vs * vs;
    }
    float rt = 1.f / fmaxf(sqrtf(nt), 1e-12f);
    float rs = 1.f / fmaxf(sqrtf(ns), 1e-12f);
    for (int j = 0; j < 21; ++j) {
      int idx2 = (i <= j) ? i * 21 + j : j * 21 + i;
      float d = gs[idx2] * rs - gt[idx2] * rt;
      ic += d * d;
    }
  }
  int lane = tid & 63, wv = tid >> 6;
#pragma unroll
  for (int m = 32; m; m >>= 1) { sa += __shfl_xor(sa, m); ic += __shfl_xor(ic, m); }
  if (lane == 0) red[wv] = sa;
  __syncthreads();
  if (tid == 0) { float s = 0.f; for (int w = 0; w < 16; ++w) s += red[w]; out2[1] = s * (1.0f / 16777216.0f); }
  __syncthreads();
  if (lane == 0) red[wv] = ic;
  __syncthreads();
  if (tid == 0) { float s = 0.f; for (int w = 0; w < 16; ++w) s += red[w]; out2[0] = s * (1.0f / 336.0f); }
}

// ---------- launch ----------
extern "C" void kernel_launch(void* const* d_in, const int* in_sizes, int n_in,
                              void* d_out, int out_size, void* d_ws, size_t ws_size,
                              hipStream_t stream) {
  const float* TF = (const float*)d_in[0];
  const float* SF = (const float*)d_in[1];
  const float* t_out = (const float*)d_in[2];
  const float* s_out = (const float*)d_in[3];
  float* out = (float*)d_out;
  char* ws = (char*)d_ws;

  // ws layout (bytes):
  //   0        : nT    [16][1024] f32  (65536)
  //   65536    : nS    [16][1024] f32  (65536)
  //   131072   : cross [16][1024] f32  (65536)
  //   196608   : G     [32][441]  f32  (56448, zeroed through 253056)
  //   253184   : sqrtFc [16384]   f32  (65536)
  //   318720   : Wt bf16 [16][1024][512] (16777216)
  //   17095936 : Ws bf16 [16][1024][512] (16777216)  -> total ~33.9 MB
  float* nT = (float*)(ws + 0);
  float* nS = (float*)(ws + 65536);
  float* cross = (float*)(ws + 131072);
  float* G = (float*)(ws + 196608);
  float* sqrtFc = (float*)(ws + 253184);
  __hip_bfloat16* Wt = (__hip_bfloat16*)(ws + 318720);
  __hip_bfloat16* Ws = (__hip_bfloat16*)(ws + 318720 + 16777216);

  (void)hipMemsetAsync(ws, 0, 253056, stream);   // nT, nS, cross, G

  fc_kernel<<<4096, 256, 0, stream>>>(TF, SF, sqrtFc);
  wprep2_kernel<<<dim3(16, 8, 32), 256, 0, stream>>>(TF, SF, sqrtFc, Wt, Ws);
  syrk_fused_kernel<<<576, 512, 0, stream>>>(Wt, Ws, nT, nS, cross);
  icgram2_kernel<<<dim3(32, 32), 256, 0, stream>>>(t_out, s_out, G, out);
  finalize_kernel<<<1, 1024, 0, stream>>>(G, nT, nS, cross, out + 5505024);
}